// Round 17
// baseline (208.491 us; speedup 1.0000x reference)
//
#include <hip/hip_runtime.h>
#include <hip/hip_fp16.h>

#define ALPHA 0.2f
#define BKT_CAP 8192

typedef __attribute__((ext_vector_type(8))) _Float16 f16x8;
typedef __attribute__((ext_vector_type(4))) float f32x4;

static __device__ __forceinline__ float leaky_f(float v) {
  return v >= 0.0f ? v : ALPHA * v;
}

typedef const __attribute__((address_space(1))) unsigned char* gas1_t;
typedef __attribute__((address_space(3))) unsigned char* las3_t;
static __device__ __forceinline__ void gll16(const void* g, void* l) {
  __builtin_amdgcn_global_load_lds((gas1_t)g, (las3_t)l, 16, 0, 0);
}

// ================= bucketed CSR build, fixed-capacity windows =================
__global__ __launch_bounds__(256) void bkt_scatter(const int* __restrict__ src,
                                                   const int* __restrict__ dst,
                                                   int* __restrict__ bktcur,
                                                   unsigned* __restrict__ ebuf, int E) {
  __shared__ int hist[256], sc[256], lofs[256], cur[256], base[256];
  __shared__ unsigned stage[2048];
  int t = threadIdx.x;
  int e0 = blockIdx.x * 2048;
  int n = min(2048, E - e0);
  hist[t] = 0;
  __syncthreads();
  int myb[8];
  unsigned myw[8];
  #pragma unroll
  for (int k = 0; k < 8; ++k) {
    int j = t + k * 256;
    if (j < n) {
      int d = dst[e0 + j];
      myb[k] = d >> 8;
      myw[k] = (unsigned)src[e0 + j] | ((unsigned)(d & 255) << 16);
      atomicAdd(&hist[myb[k]], 1);
    } else myb[k] = -1;
  }
  __syncthreads();
  int v = hist[t];
  sc[t] = v;
  __syncthreads();
  for (int d = 1; d < 256; d <<= 1) {
    int u = (t >= d) ? sc[t - d] : 0;
    __syncthreads();
    sc[t] += u;
    __syncthreads();
  }
  lofs[t] = sc[t] - v;
  cur[t] = sc[t] - v;
  if (v > 0) base[t] = atomicAdd(&bktcur[t], v);
  __syncthreads();
  #pragma unroll
  for (int k = 0; k < 8; ++k)
    if (myb[k] >= 0) stage[atomicAdd(&cur[myb[k]], 1)] = myw[k];
  __syncthreads();
  for (int j = t; j < n; j += 256) {
    int lo = 0, hi = 255;
    while (lo < hi) {
      int mid = (lo + hi + 1) >> 1;
      if (lofs[mid] <= j) lo = mid; else hi = mid - 1;
    }
    ebuf[base[lo] + (j - lofs[lo])] = stage[j];
  }
}

__global__ __launch_bounds__(256) void bkt_build(const unsigned* __restrict__ ebuf,
                                                 const int* __restrict__ bktcur,
                                                 int* __restrict__ off,
                                                 int* __restrict__ deg,
                                                 int* __restrict__ csr, int M) {
  __shared__ int hist[256], sc[256], cur[256];
  __shared__ unsigned stage[8192];
  int b = blockIdx.x, t = threadIdx.x;
  int base = b * BKT_CAP;
  int cnt = bktcur[b] - base;
  hist[t] = 0;
  __syncthreads();
  for (int j = t; j < cnt; j += 256) {
    unsigned w = ebuf[base + j];
    if (j < 8192) stage[j] = w;
    atomicAdd(&hist[(w >> 16) & 255], 1);
  }
  __syncthreads();
  int v = hist[t];
  sc[t] = v;
  __syncthreads();
  for (int d = 1; d < 256; d <<= 1) {
    int u = (t >= d) ? sc[t - d] : 0;
    __syncthreads();
    sc[t] += u;
    __syncthreads();
  }
  int excl = sc[t] - v;
  cur[t] = excl;
  int node = (b << 8) + t;
  if (node < M) {
    off[node] = base + excl;
    deg[node] = v;
  }
  __syncthreads();
  for (int j = t; j < cnt; j += 256) {
    unsigned w = (j < 8192) ? stage[j] : ebuf[base + j];
    int s = atomicAdd(&cur[(w >> 16) & 255], 1);
    csr[base + s] = (int)(w & 0xFFFFu);
  }
}

// ---------- fused prep: seed bktcur + 96 weight tiles + x->fp16 ----------
struct PrepArgs {
  const float *x, *W1, *W2, *W3, *W4;
  _Float16 *XH, *w1h, *w2h, *w3h, *w4h;
  int* bktcur;
  int n8;
};

static __device__ void prep_tile_dev(const float* __restrict__ W, _Float16* __restrict__ Wh,
                                     int K, int N, int kt, int nt, unsigned char* shmem) {
  float (*T)[65] = reinterpret_cast<float (*)[65]>(shmem);
  int k0 = kt * 32, n0 = nt * 64;
  int t = threadIdx.x;
  int nn = t & 63, kk0 = t >> 6;
  #pragma unroll
  for (int i = 0; i < 8; ++i) {
    int kk = kk0 + i * 4;
    T[kk][nn] = W[(size_t)(k0 + kk) * N + n0 + nn];
  }
  __syncthreads();
  int kk = t & 31, nb = t >> 5;
  #pragma unroll
  for (int i = 0; i < 8; ++i) {
    int n2 = nb + i * 8;
    Wh[(size_t)(n0 + n2) * K + k0 + kk] = (_Float16)T[kk][n2];
  }
}

__global__ __launch_bounds__(256) void prep_all(PrepArgs a) {
  __shared__ __align__(16) unsigned char shmem[8448];
  int bid = blockIdx.x;
  if (bid == 0) a.bktcur[threadIdx.x] = threadIdx.x * BKT_CAP;
  if (bid < 96) {
    if (bid < 16)      prep_tile_dev(a.W1, a.w1h, 128, 256, bid & 3, bid >> 2, shmem);
    else if (bid < 48) { int u = bid - 16; prep_tile_dev(a.W2, a.w2h, 256, 256, u & 7, u >> 3, shmem); }
    else if (bid < 80) { int u = bid - 48; prep_tile_dev(a.W3, a.w3h, 256, 256, u & 7, u >> 3, shmem); }
    else               { int u = bid - 80; prep_tile_dev(a.W4, a.w4h, 256, 128, u & 7, u >> 3, shmem); }
  } else {
    int i = (bid - 96) * 256 + threadIdx.x;
    if (i < a.n8) {
      const float4* p = reinterpret_cast<const float4*>(a.x) + (size_t)i * 2;
      float4 v0 = p[0], v1 = p[1];
      float f[8] = {v0.x, v0.y, v0.z, v0.w, v1.x, v1.y, v1.z, v1.w};
      f16x8 o;
      #pragma unroll
      for (int q = 0; q < 8; ++q) o[q] = (_Float16)f[q];
      reinterpret_cast<f16x8*>(a.XH)[i] = o;
    }
  }
}

// ---------- aggregation: agg[i] = x[i] + sum_p x[csr[p]]; fp16 in/out ----------
// NPASS>1: iterate src-index ranges so each range is per-XCD-L2-resident.
// Range checks are uniform per node-group (csr value broadcast) -> no divergence.
template <int F8, int NPASS>
__global__ __launch_bounds__(256) void gather_f16(const _Float16* __restrict__ xh,
                                                  const int* __restrict__ off,
                                                  const int* __restrict__ deg,
                                                  const int* __restrict__ csr,
                                                  _Float16* __restrict__ agg, int M) {
  constexpr int GP = 256 / F8;
  int g = threadIdx.x / F8;
  int lane = threadIdx.x % F8;
  int node = blockIdx.x * GP + g;
  if (node >= M) return;
  const f16x8* xv = reinterpret_cast<const f16x8*>(xh);
  float a0[8], a1[8], a2[8], a3[8];
  {
    f16x8 v = xv[(size_t)node * F8 + lane];
    #pragma unroll
    for (int i = 0; i < 8; ++i) { a0[i] = (float)v[i]; a1[i] = 0.f; a2[i] = 0.f; a3[i] = 0.f; }
  }
  const int p0 = off[node], p1 = p0 + deg[node];
  const int RS = (M + NPASS - 1) / NPASS;
  #pragma unroll
  for (int pass = 0; pass < NPASS; ++pass) {
    const int lo = pass * RS;
    const int hi = (NPASS == 1) ? M : min(lo + RS, M);
    int p = p0;
    for (; p + 4 <= p1; p += 4) {
      int s0 = csr[p], s1 = csr[p + 1], s2 = csr[p + 2], s3 = csr[p + 3];
      if (NPASS == 1 || (s0 >= lo && s0 < hi)) {
        f16x8 v = xv[(size_t)s0 * F8 + lane];
        #pragma unroll
        for (int i = 0; i < 8; ++i) a0[i] += (float)v[i];
      }
      if (NPASS == 1 || (s1 >= lo && s1 < hi)) {
        f16x8 v = xv[(size_t)s1 * F8 + lane];
        #pragma unroll
        for (int i = 0; i < 8; ++i) a1[i] += (float)v[i];
      }
      if (NPASS == 1 || (s2 >= lo && s2 < hi)) {
        f16x8 v = xv[(size_t)s2 * F8 + lane];
        #pragma unroll
        for (int i = 0; i < 8; ++i) a2[i] += (float)v[i];
      }
      if (NPASS == 1 || (s3 >= lo && s3 < hi)) {
        f16x8 v = xv[(size_t)s3 * F8 + lane];
        #pragma unroll
        for (int i = 0; i < 8; ++i) a3[i] += (float)v[i];
      }
    }
    for (; p < p1; ++p) {
      int s = csr[p];
      if (NPASS == 1 || (s >= lo && s < hi)) {
        f16x8 v = xv[(size_t)s * F8 + lane];
        #pragma unroll
        for (int i = 0; i < 8; ++i) a0[i] += (float)v[i];
      }
    }
  }
  f16x8 o;
  #pragma unroll
  for (int i = 0; i < 8; ++i) o[i] = (_Float16)((a0[i] + a1[i]) + (a2[i] + a3[i]));
  reinterpret_cast<f16x8*>(agg)[(size_t)node * F8 + lane] = o;
}

// ================= fused 2-layer MLP kernel (unchanged from R15/R16) =================
#define TPITCH 264
template <int LAYER>
__global__ __launch_bounds__(256, 2) void mlp_fused(const _Float16* __restrict__ AG,
                                                    const _Float16* __restrict__ Wa,
                                                    const float* __restrict__ ba,
                                                    const _Float16* __restrict__ Wb,
                                                    const float* __restrict__ bb,
                                                    _Float16* __restrict__ H,
                                                    const float* __restrict__ w5,
                                                    const float* __restrict__ b5p,
                                                    float* __restrict__ out, int M) {
  constexpr int K1 = LAYER ? 256 : 128;
  constexpr int N2 = LAYER ? 128 : 256;
  constexpr int MI2 = N2 / 64;
  __shared__ __align__(16) unsigned char smem[4096 + 16384 + 64 * TPITCH * 2];
  __shared__ float part_s[64][4];
  _Float16* Tlds = (_Float16*)(smem + 20480);

  const int tid = threadIdx.x;
  const int bm = blockIdx.x * 64;
  const int lane = tid & 63;
  const int wave = tid >> 6;
  const int lrow = lane & 15;
  const int lslot = lane >> 4;

  // ---------------- stage 1: T = leaky(AG@Wa + ba) ----------------
  f32x4 acc1[4][4];
  #pragma unroll
  for (int mi = 0; mi < 4; ++mi)
    #pragma unroll
    for (int ni = 0; ni < 4; ++ni)
      acc1[mi][ni] = (f32x4){0.f, 0.f, 0.f, 0.f};

  for (int k0 = 0; k0 < K1; k0 += 32) {
    {
      int row = tid >> 2, s = tid & 3;
      int sg = s ^ ((row >> 1) & 3);
      gll16(AG + (size_t)(bm + row) * K1 + k0 + sg * 8, smem + tid * 16);
    }
    #pragma unroll
    for (int h = 0; h < 4; ++h) {
      int p = tid + h * 256;
      int row = p >> 2, s = p & 3;
      int sg = s ^ ((row >> 1) & 3);
      gll16(Wa + (size_t)row * K1 + k0 + sg * 8, smem + 4096 + p * 16);
    }
    __syncthreads();
    const _Float16* A_s = (const _Float16*)smem;
    const _Float16* B_s = (const _Float16*)(smem + 4096);
    f16x8 fw[4], fa[4];
    #pragma unroll
    for (int mi = 0; mi < 4; ++mi) {
      int r = wave * 64 + mi * 16 + lrow;
      int off = r * 32 + ((lslot ^ ((r >> 1) & 3)) << 3);
      fw[mi] = *reinterpret_cast<const f16x8*>(&B_s[off]);
    }
    #pragma unroll
    for (int ni = 0; ni < 4; ++ni) {
      int r = ni * 16 + lrow;
      int off = r * 32 + ((lslot ^ ((r >> 1) & 3)) << 3);
      fa[ni] = *reinterpret_cast<const f16x8*>(&A_s[off]);
    }
    #pragma unroll
    for (int mi = 0; mi < 4; ++mi)
      #pragma unroll
      for (int ni = 0; ni < 4; ++ni)
        acc1[mi][ni] = __builtin_amdgcn_mfma_f32_16x16x32_f16(fw[mi], fa[ni], acc1[mi][ni], 0, 0, 0);
    __syncthreads();
  }
  {
    #pragma unroll
    for (int mi = 0; mi < 4; ++mi) {
      float bv[4];
      #pragma unroll
      for (int j = 0; j < 4; ++j) bv[j] = ba[wave * 64 + mi * 16 + lslot * 4 + j];
      #pragma unroll
      for (int ni = 0; ni < 4; ++ni) {
        unsigned short h[4];
        #pragma unroll
        for (int j = 0; j < 4; ++j)
          h[j] = __half_as_ushort(__float2half_rn(leaky_f(acc1[mi][ni][j] + bv[j])));
        uint2 w;
        w.x = (unsigned)h[0] | ((unsigned)h[1] << 16);
        w.y = (unsigned)h[2] | ((unsigned)h[3] << 16);
        int r = ni * 16 + lrow;
        int c = wave * 64 + mi * 16 + lslot * 4;
        *reinterpret_cast<uint2*>(&Tlds[r * TPITCH + c]) = w;
      }
    }
  }
  __syncthreads();

  // ---------------- stage 2: O = leaky(T@Wb + bb) ----------------
  f32x4 acc2[MI2][4];
  #pragma unroll
  for (int mi = 0; mi < MI2; ++mi)
    #pragma unroll
    for (int ni = 0; ni < 4; ++ni)
      acc2[mi][ni] = (f32x4){0.f, 0.f, 0.f, 0.f};

  for (int k0 = 0; k0 < 256; k0 += 32) {
    #pragma unroll
    for (int h = 0; h < N2 / 64; ++h) {
      int p = tid + h * 256;
      int row = p >> 2, s = p & 3;
      int sg = s ^ ((row >> 1) & 3);
      gll16(Wb + (size_t)row * 256 + k0 + sg * 8, smem + 4096 + p * 16);
    }
    __syncthreads();
    const _Float16* B_s = (const _Float16*)(smem + 4096);
    f16x8 fw[MI2], ft[4];
    #pragma unroll
    for (int mi = 0; mi < MI2; ++mi) {
      int r = wave * (N2 / 4) + mi * 16 + lrow;
      int off = r * 32 + ((lslot ^ ((r >> 1) & 3)) << 3);
      fw[mi] = *reinterpret_cast<const f16x8*>(&B_s[off]);
    }
    #pragma unroll
    for (int ni = 0; ni < 4; ++ni) {
      int r = ni * 16 + lrow;
      ft[ni] = *reinterpret_cast<const f16x8*>(&Tlds[r * TPITCH + k0 + lslot * 8]);
    }
    #pragma unroll
    for (int mi = 0; mi < MI2; ++mi)
      #pragma unroll
      for (int ni = 0; ni < 4; ++ni)
        acc2[mi][ni] = __builtin_amdgcn_mfma_f32_16x16x32_f16(fw[mi], ft[ni], acc2[mi][ni], 0, 0, 0);
    __syncthreads();
  }

  if (LAYER == 0) {
    #pragma unroll
    for (int mi = 0; mi < 4; ++mi) {
      float bv[4];
      #pragma unroll
      for (int j = 0; j < 4; ++j) bv[j] = bb[wave * 64 + mi * 16 + lslot * 4 + j];
      #pragma unroll
      for (int ni = 0; ni < 4; ++ni) {
        unsigned short h[4];
        #pragma unroll
        for (int j = 0; j < 4; ++j)
          h[j] = __half_as_ushort(__float2half_rn(leaky_f(acc2[mi][ni][j] + bv[j])));
        uint2 w;
        w.x = (unsigned)h[0] | ((unsigned)h[1] << 16);
        w.y = (unsigned)h[2] | ((unsigned)h[3] << 16);
        int r = ni * 16 + lrow;
        int c = wave * 64 + mi * 16 + lslot * 4;
        *reinterpret_cast<uint2*>(&Tlds[r * TPITCH + c]) = w;
      }
    }
    __syncthreads();
    #pragma unroll
    for (int rep = 0; rep < 8; ++rep) {
      int idx = tid + rep * 256;
      int row = idx >> 5, q = idx & 31;
      if (bm + row < M) {
        *reinterpret_cast<uint4*>(&H[(size_t)(bm + row) * 256 + q * 8]) =
            *reinterpret_cast<const uint4*>(&Tlds[row * TPITCH + q * 8]);
      }
    }
  } else {
    float s[4] = {0.f, 0.f, 0.f, 0.f};
    #pragma unroll
    for (int mi = 0; mi < MI2; ++mi) {
      float bv[4], wv[4];
      #pragma unroll
      for (int j = 0; j < 4; ++j) {
        int n = wave * 32 + mi * 16 + lslot * 4 + j;
        bv[j] = bb[n];
        wv[j] = w5[n];
      }
      #pragma unroll
      for (int ni = 0; ni < 4; ++ni)
        #pragma unroll
        for (int j = 0; j < 4; ++j)
          s[ni] += leaky_f(acc2[mi][ni][j] + bv[j]) * wv[j];
    }
    #pragma unroll
    for (int ni = 0; ni < 4; ++ni) {
      s[ni] += __shfl_xor(s[ni], 16, 64);
      s[ni] += __shfl_xor(s[ni], 32, 64);
    }
    if (lane < 16) {
      #pragma unroll
      for (int ni = 0; ni < 4; ++ni) part_s[ni * 16 + lrow][wave] = s[ni];
    }
    __syncthreads();
    if (tid < 64) {
      int row = bm + tid;
      if (row < M)
        out[row] = part_s[tid][0] + part_s[tid][1] + part_s[tid][2] + part_s[tid][3] + b5p[0];
    }
  }
}

extern "C" void kernel_launch(void* const* d_in, const int* in_sizes, int n_in,
                              void* d_out, int out_size, void* d_ws, size_t ws_size,
                              hipStream_t stream) {
  const float* x  = (const float*)d_in[0];
  const int*   ei = (const int*)d_in[2];
  const float* W1 = (const float*)d_in[3];
  const float* b1 = (const float*)d_in[4];
  const float* W2 = (const float*)d_in[5];
  const float* b2 = (const float*)d_in[6];
  const float* W3 = (const float*)d_in[7];
  const float* b3 = (const float*)d_in[8];
  const float* W4 = (const float*)d_in[9];
  const float* b4 = (const float*)d_in[10];
  const float* W5 = (const float*)d_in[11];
  const float* b5 = (const float*)d_in[12];
  float* out = (float*)d_out;

  const int M = in_sizes[0] / 128;  // 50000
  const int E = in_sizes[2] / 2;    // 800000
  const int* src = ei;
  const int* dst = ei + E;
  const int MB64 = (M + 63) / 64;          // 782
  const int MR = MB64 * 64;                // 50048
  const int NBKT = (M + 255) >> 8;         // 196

  // ---- workspace layout (16B aligned) ----
  _Float16* w1h = (_Float16*)d_ws;                    // 256*128
  _Float16* w2h = w1h + 256 * 128;                    // 256*256
  _Float16* w3h = w2h + 256 * 256;                    // 256*256
  _Float16* w4h = w3h + 256 * 256;                    // 128*256
  _Float16* XH  = w4h + 128 * 256;                    // M*128 fp16
  _Float16* AG1 = XH + (size_t)M * 128;               // MR*128
  _Float16* H2  = AG1 + (size_t)MR * 128;             // MR*256 (h1)
  _Float16* AG2 = H2 + (size_t)MR * 256;              // MR*256
  int* off     = (int*)(AG2 + (size_t)MR * 256);      // M
  int* deg     = off + M;                             // M
  int* csr     = deg + M;                             // NBKT*BKT_CAP
  unsigned* ebuf = (unsigned*)(csr + (size_t)NBKT * BKT_CAP);  // NBKT*BKT_CAP
  int* bktcur  = (int*)(ebuf + (size_t)NBKT * BKT_CAP);        // 256

  dim3 blk(256);

  // ---- fused prep: seed bktcur + weights (96 tiles) + x->fp16 ----
  {
    PrepArgs pa;
    pa.x = x; pa.W1 = W1; pa.W2 = W2; pa.W3 = W3; pa.W4 = W4;
    pa.XH = XH; pa.w1h = w1h; pa.w2h = w2h; pa.w3h = w3h; pa.w4h = w4h;
    pa.bktcur = bktcur;
    pa.n8 = M * 128 / 8;
    prep_all<<<96 + (pa.n8 + 255) / 256, blk, 0, stream>>>(pa);
  }

  // ---- bucketed CSR build (2 dispatches) ----
  const int EB = (E + 2047) / 2048;  // 391
  bkt_scatter<<<EB, blk, 0, stream>>>(src, dst, bktcur, ebuf, E);
  bkt_build<<<NBKT, blk, 0, stream>>>(ebuf, bktcur, off, deg, csr, M);

  // ---- layer 1: multipass gather (x table thrashes L2 otherwise) + fused MLP ----
  gather_f16<16, 4><<<(M * 16 + 255) / 256, blk, 0, stream>>>(XH, off, deg, csr, AG1, M);
  mlp_fused<0><<<MB64, blk, 0, stream>>>(AG1, w1h, b1, w2h, b2, H2,
                                         nullptr, nullptr, nullptr, M);
  // ---- layer 2: gather (at unique-rows floor) + fused MLP + final linear ----
  gather_f16<32, 1><<<(M * 32 + 255) / 256, blk, 0, stream>>>(H2, off, deg, csr, AG2, M);
  mlp_fused<1><<<MB64, blk, 0, stream>>>(AG2, w3h, b3, w4h, b4, nullptr,
                                         W5, b5, out, M);
}

// Round 18
// 171.527 us; speedup vs baseline: 1.2155x; 1.2155x over previous
//
#include <hip/hip_runtime.h>
#include <hip/hip_fp16.h>

#define ALPHA 0.2f
#define BKT_CAP 8192  // fixed per-bucket window; mean 4096, sigma ~64 -> 64-sigma margin

typedef __attribute__((ext_vector_type(8))) _Float16 f16x8;
typedef __attribute__((ext_vector_type(4))) float f32x4;

static __device__ __forceinline__ float leaky_f(float v) {
  return v >= 0.0f ? v : ALPHA * v;
}

typedef const __attribute__((address_space(1))) unsigned char* gas1_t;
typedef __attribute__((address_space(3))) unsigned char* las3_t;
static __device__ __forceinline__ void gll16(const void* g, void* l) {
  __builtin_amdgcn_global_load_lds((gas1_t)g, (las3_t)l, 16, 0, 0);
}

// ================= bucketed CSR build, fixed-capacity windows =================
// bucket(d) = d>>8; word = src | (d&255)<<16; window b = [b*BKT_CAP, b*BKT_CAP+cnt)

__global__ __launch_bounds__(256) void bkt_scatter(const int* __restrict__ src,
                                                   const int* __restrict__ dst,
                                                   int* __restrict__ bktcur,
                                                   unsigned* __restrict__ ebuf, int E) {
  __shared__ int hist[256], sc[256], lofs[256], cur[256], base[256];
  __shared__ unsigned stage[2048];
  int t = threadIdx.x;
  int e0 = blockIdx.x * 2048;
  int n = min(2048, E - e0);
  hist[t] = 0;
  __syncthreads();
  int myb[8];
  unsigned myw[8];
  #pragma unroll
  for (int k = 0; k < 8; ++k) {
    int j = t + k * 256;
    if (j < n) {
      int d = dst[e0 + j];
      myb[k] = d >> 8;
      myw[k] = (unsigned)src[e0 + j] | ((unsigned)(d & 255) << 16);
      atomicAdd(&hist[myb[k]], 1);
    } else myb[k] = -1;
  }
  __syncthreads();
  int v = hist[t];
  sc[t] = v;
  __syncthreads();
  for (int d = 1; d < 256; d <<= 1) {
    int u = (t >= d) ? sc[t - d] : 0;
    __syncthreads();
    sc[t] += u;
    __syncthreads();
  }
  lofs[t] = sc[t] - v;
  cur[t] = sc[t] - v;
  if (v > 0) base[t] = atomicAdd(&bktcur[t], v);
  __syncthreads();
  #pragma unroll
  for (int k = 0; k < 8; ++k)
    if (myb[k] >= 0) stage[atomicAdd(&cur[myb[k]], 1)] = myw[k];
  __syncthreads();
  for (int j = t; j < n; j += 256) {
    int lo = 0, hi = 255;
    while (lo < hi) {
      int mid = (lo + hi + 1) >> 1;
      if (lofs[mid] <= j) lo = mid; else hi = mid - 1;
    }
    ebuf[base[lo] + (j - lofs[lo])] = stage[j];
  }
}

__global__ __launch_bounds__(256) void bkt_build(const unsigned* __restrict__ ebuf,
                                                 const int* __restrict__ bktcur,
                                                 int* __restrict__ off,
                                                 int* __restrict__ deg,
                                                 int* __restrict__ csr, int M) {
  __shared__ int hist[256], sc[256], cur[256];
  __shared__ unsigned stage[8192];
  int b = blockIdx.x, t = threadIdx.x;
  int base = b * BKT_CAP;
  int cnt = bktcur[b] - base;
  hist[t] = 0;
  __syncthreads();
  for (int j = t; j < cnt; j += 256) {
    unsigned w = ebuf[base + j];
    if (j < 8192) stage[j] = w;
    atomicAdd(&hist[(w >> 16) & 255], 1);
  }
  __syncthreads();
  int v = hist[t];
  sc[t] = v;
  __syncthreads();
  for (int d = 1; d < 256; d <<= 1) {
    int u = (t >= d) ? sc[t - d] : 0;
    __syncthreads();
    sc[t] += u;
    __syncthreads();
  }
  int excl = sc[t] - v;
  cur[t] = excl;
  int node = (b << 8) + t;
  if (node < M) {
    off[node] = base + excl;
    deg[node] = v;
  }
  __syncthreads();
  for (int j = t; j < cnt; j += 256) {
    unsigned w = (j < 8192) ? stage[j] : ebuf[base + j];
    int s = atomicAdd(&cur[(w >> 16) & 255], 1);
    csr[base + s] = (int)(w & 0xFFFFu);
  }
}

// ---------- fused prep: seed bktcur + 96 weight tiles + x->fp16 ----------
struct PrepArgs {
  const float *x, *W1, *W2, *W3, *W4;
  _Float16 *XH, *w1h, *w2h, *w3h, *w4h;
  int* bktcur;
  int n8;
};

static __device__ void prep_tile_dev(const float* __restrict__ W, _Float16* __restrict__ Wh,
                                     int K, int N, int kt, int nt, unsigned char* shmem) {
  float (*T)[65] = reinterpret_cast<float (*)[65]>(shmem);
  int k0 = kt * 32, n0 = nt * 64;
  int t = threadIdx.x;
  int nn = t & 63, kk0 = t >> 6;
  #pragma unroll
  for (int i = 0; i < 8; ++i) {
    int kk = kk0 + i * 4;
    T[kk][nn] = W[(size_t)(k0 + kk) * N + n0 + nn];
  }
  __syncthreads();
  int kk = t & 31, nb = t >> 5;
  #pragma unroll
  for (int i = 0; i < 8; ++i) {
    int n2 = nb + i * 8;
    Wh[(size_t)(n0 + n2) * K + k0 + kk] = (_Float16)T[kk][n2];
  }
}

__global__ __launch_bounds__(256) void prep_all(PrepArgs a) {
  __shared__ __align__(16) unsigned char shmem[8448];
  int bid = blockIdx.x;
  if (bid == 0) a.bktcur[threadIdx.x] = threadIdx.x * BKT_CAP;
  if (bid < 96) {
    if (bid < 16)      prep_tile_dev(a.W1, a.w1h, 128, 256, bid & 3, bid >> 2, shmem);
    else if (bid < 48) { int u = bid - 16; prep_tile_dev(a.W2, a.w2h, 256, 256, u & 7, u >> 3, shmem); }
    else if (bid < 80) { int u = bid - 48; prep_tile_dev(a.W3, a.w3h, 256, 256, u & 7, u >> 3, shmem); }
    else               { int u = bid - 80; prep_tile_dev(a.W4, a.w4h, 256, 128, u & 7, u >> 3, shmem); }
  } else {
    int i = (bid - 96) * 256 + threadIdx.x;
    if (i < a.n8) {
      const float4* p = reinterpret_cast<const float4*>(a.x) + (size_t)i * 2;
      float4 v0 = p[0], v1 = p[1];
      float f[8] = {v0.x, v0.y, v0.z, v0.w, v1.x, v1.y, v1.z, v1.w};
      f16x8 o;
      #pragma unroll
      for (int q = 0; q < 8; ++q) o[q] = (_Float16)f[q];
      reinterpret_cast<f16x8*>(a.XH)[i] = o;
    }
  }
}

// ---------- aggregation: agg[i] = x[i] + sum_p x[csr[p]]; fp16 in/out ----------
template <int F8>
__global__ __launch_bounds__(256) void gather_f16(const _Float16* __restrict__ xh,
                                                  const int* __restrict__ off,
                                                  const int* __restrict__ deg,
                                                  const int* __restrict__ csr,
                                                  _Float16* __restrict__ agg, int M) {
  constexpr int GP = 256 / F8;
  int g = threadIdx.x / F8;
  int lane = threadIdx.x % F8;
  int node = blockIdx.x * GP + g;
  if (node >= M) return;
  const f16x8* xv = reinterpret_cast<const f16x8*>(xh);
  float a0[8], a1[8], a2[8], a3[8];
  {
    f16x8 v = xv[(size_t)node * F8 + lane];
    #pragma unroll
    for (int i = 0; i < 8; ++i) { a0[i] = (float)v[i]; a1[i] = 0.f; a2[i] = 0.f; a3[i] = 0.f; }
  }
  int p = off[node], p1 = p + deg[node];
  for (; p + 4 <= p1; p += 4) {
    int s0 = csr[p], s1 = csr[p + 1], s2 = csr[p + 2], s3 = csr[p + 3];
    f16x8 v0 = xv[(size_t)s0 * F8 + lane];
    f16x8 v1 = xv[(size_t)s1 * F8 + lane];
    f16x8 v2 = xv[(size_t)s2 * F8 + lane];
    f16x8 v3 = xv[(size_t)s3 * F8 + lane];
    #pragma unroll
    for (int i = 0; i < 8; ++i) {
      a0[i] += (float)v0[i]; a1[i] += (float)v1[i];
      a2[i] += (float)v2[i]; a3[i] += (float)v3[i];
    }
  }
  for (; p < p1; ++p) {
    f16x8 v = xv[(size_t)csr[p] * F8 + lane];
    #pragma unroll
    for (int i = 0; i < 8; ++i) a0[i] += (float)v[i];
  }
  f16x8 o;
  #pragma unroll
  for (int i = 0; i < 8; ++i) o[i] = (_Float16)((a0[i] + a1[i]) + (a2[i] + a3[i]));
  reinterpret_cast<f16x8*>(agg)[(size_t)node * F8 + lane] = o;
}

// ================= fused 2-layer MLP kernel =================
#define TPITCH 264
template <int LAYER>
__global__ __launch_bounds__(256, 2) void mlp_fused(const _Float16* __restrict__ AG,
                                                    const _Float16* __restrict__ Wa,
                                                    const float* __restrict__ ba,
                                                    const _Float16* __restrict__ Wb,
                                                    const float* __restrict__ bb,
                                                    _Float16* __restrict__ H,
                                                    const float* __restrict__ w5,
                                                    const float* __restrict__ b5p,
                                                    float* __restrict__ out, int M) {
  constexpr int K1 = LAYER ? 256 : 128;
  constexpr int N2 = LAYER ? 128 : 256;
  constexpr int MI2 = N2 / 64;
  __shared__ __align__(16) unsigned char smem[4096 + 16384 + 64 * TPITCH * 2];
  __shared__ float part_s[64][4];
  _Float16* Tlds = (_Float16*)(smem + 20480);

  const int tid = threadIdx.x;
  const int bm = blockIdx.x * 64;
  const int lane = tid & 63;
  const int wave = tid >> 6;
  const int lrow = lane & 15;
  const int lslot = lane >> 4;

  // ---------------- stage 1: T = leaky(AG@Wa + ba) ----------------
  f32x4 acc1[4][4];
  #pragma unroll
  for (int mi = 0; mi < 4; ++mi)
    #pragma unroll
    for (int ni = 0; ni < 4; ++ni)
      acc1[mi][ni] = (f32x4){0.f, 0.f, 0.f, 0.f};

  for (int k0 = 0; k0 < K1; k0 += 32) {
    {
      int row = tid >> 2, s = tid & 3;
      int sg = s ^ ((row >> 1) & 3);
      gll16(AG + (size_t)(bm + row) * K1 + k0 + sg * 8, smem + tid * 16);
    }
    #pragma unroll
    for (int h = 0; h < 4; ++h) {
      int p = tid + h * 256;
      int row = p >> 2, s = p & 3;
      int sg = s ^ ((row >> 1) & 3);
      gll16(Wa + (size_t)row * K1 + k0 + sg * 8, smem + 4096 + p * 16);
    }
    __syncthreads();
    const _Float16* A_s = (const _Float16*)smem;
    const _Float16* B_s = (const _Float16*)(smem + 4096);
    f16x8 fw[4], fa[4];
    #pragma unroll
    for (int mi = 0; mi < 4; ++mi) {
      int r = wave * 64 + mi * 16 + lrow;
      int off = r * 32 + ((lslot ^ ((r >> 1) & 3)) << 3);
      fw[mi] = *reinterpret_cast<const f16x8*>(&B_s[off]);
    }
    #pragma unroll
    for (int ni = 0; ni < 4; ++ni) {
      int r = ni * 16 + lrow;
      int off = r * 32 + ((lslot ^ ((r >> 1) & 3)) << 3);
      fa[ni] = *reinterpret_cast<const f16x8*>(&A_s[off]);
    }
    #pragma unroll
    for (int mi = 0; mi < 4; ++mi)
      #pragma unroll
      for (int ni = 0; ni < 4; ++ni)
        acc1[mi][ni] = __builtin_amdgcn_mfma_f32_16x16x32_f16(fw[mi], fa[ni], acc1[mi][ni], 0, 0, 0);
    __syncthreads();
  }
  {
    #pragma unroll
    for (int mi = 0; mi < 4; ++mi) {
      float bv[4];
      #pragma unroll
      for (int j = 0; j < 4; ++j) bv[j] = ba[wave * 64 + mi * 16 + lslot * 4 + j];
      #pragma unroll
      for (int ni = 0; ni < 4; ++ni) {
        unsigned short h[4];
        #pragma unroll
        for (int j = 0; j < 4; ++j)
          h[j] = __half_as_ushort(__float2half_rn(leaky_f(acc1[mi][ni][j] + bv[j])));
        uint2 w;
        w.x = (unsigned)h[0] | ((unsigned)h[1] << 16);
        w.y = (unsigned)h[2] | ((unsigned)h[3] << 16);
        int r = ni * 16 + lrow;
        int c = wave * 64 + mi * 16 + lslot * 4;
        *reinterpret_cast<uint2*>(&Tlds[r * TPITCH + c]) = w;
      }
    }
  }
  __syncthreads();

  // ---------------- stage 2: O = leaky(T@Wb + bb) ----------------
  f32x4 acc2[MI2][4];
  #pragma unroll
  for (int mi = 0; mi < MI2; ++mi)
    #pragma unroll
    for (int ni = 0; ni < 4; ++ni)
      acc2[mi][ni] = (f32x4){0.f, 0.f, 0.f, 0.f};

  for (int k0 = 0; k0 < 256; k0 += 32) {
    #pragma unroll
    for (int h = 0; h < N2 / 64; ++h) {
      int p = tid + h * 256;
      int row = p >> 2, s = p & 3;
      int sg = s ^ ((row >> 1) & 3);
      gll16(Wb + (size_t)row * 256 + k0 + sg * 8, smem + 4096 + p * 16);
    }
    __syncthreads();
    const _Float16* B_s = (const _Float16*)(smem + 4096);
    f16x8 fw[MI2], ft[4];
    #pragma unroll
    for (int mi = 0; mi < MI2; ++mi) {
      int r = wave * (N2 / 4) + mi * 16 + lrow;
      int off = r * 32 + ((lslot ^ ((r >> 1) & 3)) << 3);
      fw[mi] = *reinterpret_cast<const f16x8*>(&B_s[off]);
    }
    #pragma unroll
    for (int ni = 0; ni < 4; ++ni) {
      int r = ni * 16 + lrow;
      ft[ni] = *reinterpret_cast<const f16x8*>(&Tlds[r * TPITCH + k0 + lslot * 8]);
    }
    #pragma unroll
    for (int mi = 0; mi < MI2; ++mi)
      #pragma unroll
      for (int ni = 0; ni < 4; ++ni)
        acc2[mi][ni] = __builtin_amdgcn_mfma_f32_16x16x32_f16(fw[mi], ft[ni], acc2[mi][ni], 0, 0, 0);
    __syncthreads();
  }

  if (LAYER == 0) {
    #pragma unroll
    for (int mi = 0; mi < 4; ++mi) {
      float bv[4];
      #pragma unroll
      for (int j = 0; j < 4; ++j) bv[j] = bb[wave * 64 + mi * 16 + lslot * 4 + j];
      #pragma unroll
      for (int ni = 0; ni < 4; ++ni) {
        unsigned short h[4];
        #pragma unroll
        for (int j = 0; j < 4; ++j)
          h[j] = __half_as_ushort(__float2half_rn(leaky_f(acc2[mi][ni][j] + bv[j])));
        uint2 w;
        w.x = (unsigned)h[0] | ((unsigned)h[1] << 16);
        w.y = (unsigned)h[2] | ((unsigned)h[3] << 16);
        int r = ni * 16 + lrow;
        int c = wave * 64 + mi * 16 + lslot * 4;
        *reinterpret_cast<uint2*>(&Tlds[r * TPITCH + c]) = w;
      }
    }
    __syncthreads();
    // 64 rows x 256 fp16 = 2048 segs of 16B (32 segs/row)
    #pragma unroll
    for (int rep = 0; rep < 8; ++rep) {
      int idx = tid + rep * 256;
      int row = idx >> 5, q = idx & 31;
      if (bm + row < M) {
        *reinterpret_cast<uint4*>(&H[(size_t)(bm + row) * 256 + q * 8]) =
            *reinterpret_cast<const uint4*>(&Tlds[row * TPITCH + q * 8]);
      }
    }
  } else {
    float s[4] = {0.f, 0.f, 0.f, 0.f};
    #pragma unroll
    for (int mi = 0; mi < MI2; ++mi) {
      float bv[4], wv[4];
      #pragma unroll
      for (int j = 0; j < 4; ++j) {
        int n = wave * 32 + mi * 16 + lslot * 4 + j;
        bv[j] = bb[n];
        wv[j] = w5[n];
      }
      #pragma unroll
      for (int ni = 0; ni < 4; ++ni)
        #pragma unroll
        for (int j = 0; j < 4; ++j)
          s[ni] += leaky_f(acc2[mi][ni][j] + bv[j]) * wv[j];
    }
    #pragma unroll
    for (int ni = 0; ni < 4; ++ni) {
      s[ni] += __shfl_xor(s[ni], 16, 64);
      s[ni] += __shfl_xor(s[ni], 32, 64);
    }
    if (lane < 16) {
      #pragma unroll
      for (int ni = 0; ni < 4; ++ni) part_s[ni * 16 + lrow][wave] = s[ni];
    }
    __syncthreads();
    if (tid < 64) {
      int row = bm + tid;
      if (row < M)
        out[row] = part_s[tid][0] + part_s[tid][1] + part_s[tid][2] + part_s[tid][3] + b5p[0];
    }
  }
}

extern "C" void kernel_launch(void* const* d_in, const int* in_sizes, int n_in,
                              void* d_out, int out_size, void* d_ws, size_t ws_size,
                              hipStream_t stream) {
  const float* x  = (const float*)d_in[0];
  const int*   ei = (const int*)d_in[2];
  const float* W1 = (const float*)d_in[3];
  const float* b1 = (const float*)d_in[4];
  const float* W2 = (const float*)d_in[5];
  const float* b2 = (const float*)d_in[6];
  const float* W3 = (const float*)d_in[7];
  const float* b3 = (const float*)d_in[8];
  const float* W4 = (const float*)d_in[9];
  const float* b4 = (const float*)d_in[10];
  const float* W5 = (const float*)d_in[11];
  const float* b5 = (const float*)d_in[12];
  float* out = (float*)d_out;

  const int M = in_sizes[0] / 128;  // 50000
  const int E = in_sizes[2] / 2;    // 800000
  const int* src = ei;
  const int* dst = ei + E;
  const int MB64 = (M + 63) / 64;          // 782
  const int MR = MB64 * 64;                // 50048
  const int NBKT = (M + 255) >> 8;         // 196

  // ---- workspace layout (16B aligned) ----
  _Float16* w1h = (_Float16*)d_ws;                    // 256*128
  _Float16* w2h = w1h + 256 * 128;                    // 256*256
  _Float16* w3h = w2h + 256 * 256;                    // 256*256
  _Float16* w4h = w3h + 256 * 256;                    // 128*256
  _Float16* XH  = w4h + 128 * 256;                    // M*128 fp16
  _Float16* AG1 = XH + (size_t)M * 128;               // MR*128
  _Float16* H2  = AG1 + (size_t)MR * 128;             // MR*256 (h1)
  _Float16* AG2 = H2 + (size_t)MR * 256;              // MR*256
  int* off     = (int*)(AG2 + (size_t)MR * 256);      // M
  int* deg     = off + M;                             // M
  int* csr     = deg + M;                             // NBKT*BKT_CAP
  unsigned* ebuf = (unsigned*)(csr + (size_t)NBKT * BKT_CAP);  // NBKT*BKT_CAP
  int* bktcur  = (int*)(ebuf + (size_t)NBKT * BKT_CAP);        // 256

  dim3 blk(256);

  // ---- fused prep: seed bktcur + weights (96 tiles) + x->fp16 ----
  {
    PrepArgs pa;
    pa.x = x; pa.W1 = W1; pa.W2 = W2; pa.W3 = W3; pa.W4 = W4;
    pa.XH = XH; pa.w1h = w1h; pa.w2h = w2h; pa.w3h = w3h; pa.w4h = w4h;
    pa.bktcur = bktcur;
    pa.n8 = M * 128 / 8;
    prep_all<<<96 + (pa.n8 + 255) / 256, blk, 0, stream>>>(pa);
  }

  // ---- bucketed CSR build (2 dispatches) ----
  const int EB = (E + 2047) / 2048;  // 391
  bkt_scatter<<<EB, blk, 0, stream>>>(src, dst, bktcur, ebuf, E);
  bkt_build<<<NBKT, blk, 0, stream>>>(ebuf, bktcur, off, deg, csr, M);

  // ---- layer 1: gather + fused MLP ----
  gather_f16<16><<<(M * 16 + 255) / 256, blk, 0, stream>>>(XH, off, deg, csr, AG1, M);
  mlp_fused<0><<<MB64, blk, 0, stream>>>(AG1, w1h, b1, w2h, b2, H2,
                                         nullptr, nullptr, nullptr, M);
  // ---- layer 2: gather + fused MLP + final linear ----
  gather_f16<32><<<(M * 32 + 255) / 256, blk, 0, stream>>>(H2, off, deg, csr, AG2, M);
  mlp_fused<1><<<MB64, blk, 0, stream>>>(AG2, w3h, b3, w4h, b4, nullptr,
                                         W5, b5, out, M);
}